// Round 1
// baseline (2457.830 us; speedup 1.0000x reference)
//
#include <hip/hip_runtime.h>

#define CIN  512
#define COUT 512
#define LAT  512
#define NB   16

// ---------- kernel A: s[b][ci] = w[b,:] . affine_w[ci,:] + ab[ci] + 1 ----------
__global__ void k_style(const float* __restrict__ w, const float* __restrict__ aw,
                        const float* __restrict__ ab, float* __restrict__ s) {
    int b = blockIdx.x, ci = threadIdx.x;
    __shared__ float wl[LAT];
    wl[ci] = w[b * LAT + ci];
    __syncthreads();
    const float4* awr = (const float4*)(aw + (size_t)ci * LAT);
    float acc = 0.f;
#pragma unroll 4
    for (int l = 0; l < LAT / 4; ++l) {
        float4 a4 = awr[l];
        const float* wp = &wl[l * 4];
        acc += a4.x * wp[0] + a4.y * wp[1] + a4.z * wp[2] + a4.w * wp[3];
    }
    s[b * CIN + ci] = acc + ab[ci] + 1.0f;
}

// ---------- kernel B1: wsq[co][ci] = sum_k weight[co,ci,k]^2 ----------
__global__ void k_wsq(const float* __restrict__ weight, float* __restrict__ wsq) {
    int co = blockIdx.x, ci = threadIdx.x;
    const float* p = weight + ((size_t)co * CIN + ci) * 9;
    float a = 0.f;
#pragma unroll
    for (int k = 0; k < 9; ++k) a += p[k] * p[k];
    wsq[co * CIN + ci] = a;
}

// ---------- kernel B2: d[b][co] = rsqrt(sum_ci s^2 * wsq + 1e-8) ----------
__global__ void k_demod(const float* __restrict__ s, const float* __restrict__ wsq,
                        float* __restrict__ d) {
    int b = blockIdx.x, co = threadIdx.x;
    __shared__ float s2[CIN];
    float sv = s[b * CIN + co];
    s2[co] = sv * sv;
    __syncthreads();
    const float4* wr = (const float4*)(wsq + (size_t)co * CIN);
    float acc = 0.f;
#pragma unroll 4
    for (int i = 0; i < CIN / 4; ++i) {
        float4 v = wr[i];
        const float* sp = &s2[i * 4];
        acc += v.x * sp[0] + v.y * sp[1] + v.z * sp[2] + v.w * sp[3];
    }
    d[b * COUT + co] = rsqrtf(acc + 1e-8f);
}

// ---------- main fused convT(stride2) + blur ----------
// y[oy][ox] = sum_{ci,ky,kx: oy=2iy+ky, ox=2ix+kx} x[ci][iy][ix] * (s[ci]*W[co][ci][ky][kx])
// out[py][px] = d * sum_{u,v} y[py-1+u][px-1+v] * bk[u]*bk[v] + bias
// Per-thread: 5-column group (c0..c0+4) x 4 rows (4rg..4rg+3) of y in registers.

#define XSTRIDE 33              // padded LDS row stride (bank-conflict free)
#define GUARD   36
#define XGSZ    (GUARD + 32 * XSTRIDE + 68)   // guards both sides
#define YSW     68
#define YSH     67

// PAR = parity of c0. Even c0: 4 x-cols (ix0=c0/2-1). Odd c0: 3 x-cols (ix0=(c0-1)/2).
template <int PAR>
__device__ __forceinline__ void rowacc(float* a, const float* xr, const float* w3) {
    if (PAR == 0) {
        a[0] = fmaf(xr[0], w3[2], a[0]);
        a[0] = fmaf(xr[1], w3[0], a[0]);
        a[1] = fmaf(xr[1], w3[1], a[1]);
        a[2] = fmaf(xr[1], w3[2], a[2]);
        a[2] = fmaf(xr[2], w3[0], a[2]);
        a[3] = fmaf(xr[2], w3[1], a[3]);
        a[4] = fmaf(xr[2], w3[2], a[4]);
        a[4] = fmaf(xr[3], w3[0], a[4]);
    } else {
        a[0] = fmaf(xr[0], w3[1], a[0]);
        a[1] = fmaf(xr[0], w3[2], a[1]);
        a[1] = fmaf(xr[1], w3[0], a[1]);
        a[2] = fmaf(xr[1], w3[1], a[2]);
        a[3] = fmaf(xr[1], w3[2], a[3]);
        a[3] = fmaf(xr[2], w3[0], a[3]);
        a[4] = fmaf(xr[2], w3[1], a[4]);
    }
}

template <int PAR>
__device__ __forceinline__ void do_ci(const float* xgp, const float* w9,
                                      float (&acc)[4][5], const bool (&xok)[3][4],
                                      int xbase) {
    float xv[3][4];
#pragma unroll
    for (int r = 0; r < 3; ++r) {
#pragma unroll
        for (int e = 0; e < (PAR ? 3 : 4); ++e)
            xv[r][e] = xok[r][e] ? xgp[xbase + r * XSTRIDE + e] : 0.0f;
    }
    // y rows of this thread: oy = 4rg + {0,1,2,3}; xv rows are iy = 2rg-1+{0,1,2}
    rowacc<PAR>(acc[0], xv[1], w9 + 0);  // oy even, ky=0 -> iy=2rg
    rowacc<PAR>(acc[0], xv[0], w9 + 6);  // oy even, ky=2 -> iy=2rg-1
    rowacc<PAR>(acc[1], xv[1], w9 + 3);  // oy odd,  ky=1 -> iy=2rg
    rowacc<PAR>(acc[2], xv[2], w9 + 0);  // ky=0 -> iy=2rg+1
    rowacc<PAR>(acc[2], xv[1], w9 + 6);  // ky=2 -> iy=2rg
    rowacc<PAR>(acc[3], xv[2], w9 + 3);  // ky=1 -> iy=2rg+1
}

__launch_bounds__(256, 4)
__global__ void k_main(const float* __restrict__ x, const float* __restrict__ weight,
                       const float* __restrict__ s, const float* __restrict__ dmod,
                       const float* __restrict__ bias, float* __restrict__ out) {
    const int bid = blockIdx.x;
    const int b = bid >> 9, co = bid & 511;
    const int t = threadIdx.x;

    __shared__ float xg[XGSZ];
    __shared__ float ys[YSH * YSW];

    // zero the padded y buffer (edges must be 0 for the blur)
    for (int i = t; i < YSH * YSW; i += 256) ys[i] = 0.f;

    // thread -> (colgroup cg, rowgroup rg); waves 0,1 = even cg, waves 2,3 = odd cg
    int slot, cg, rg;
    bool active;
    if (t < 128) { slot = t;       active = slot < 119; cg = 2 * (slot / 17);     rg = slot % 17; }
    else         { slot = t - 128; active = slot < 102; cg = 2 * (slot / 17) + 1; rg = slot % 17; }
    if (!active) { cg = 0; rg = 0; }
    const int c0  = 5 * cg;
    const int ix0 = (c0 & 1) ? (c0 - 1) / 2 : c0 / 2 - 1;
    const int iy0 = 2 * rg - 1;
    const int xbase = iy0 * XSTRIDE + ix0;

    bool xok[3][4];
#pragma unroll
    for (int r = 0; r < 3; ++r)
#pragma unroll
        for (int e = 0; e < 4; ++e)
            xok[r][e] = ((unsigned)(iy0 + r) < 32u) && ((unsigned)(ix0 + e) < 32u);

    float acc[4][5];
#pragma unroll
    for (int r = 0; r < 4; ++r)
#pragma unroll
        for (int c = 0; c < 5; ++c) acc[r][c] = 0.f;

    const float* xplane = x + (size_t)(b * CIN) * 1024;
    const float* wrow   = weight + (size_t)(co * CIN) * 9;
    const float* srow   = s + b * CIN;

    // register prefetch of ci=0 x tile (16B per thread covers the 4KB plane)
    float4 xv4 = ((const float4*)xplane)[t];
    const int st_r = t >> 3, st_c = (t & 7) * 4;
    float* stp = &xg[GUARD + st_r * XSTRIDE + st_c];

    for (int ci = 0; ci < CIN; ++ci) {
        __syncthreads();               // xg free (previous compute done)
        stp[0] = xv4.x; stp[1] = xv4.y; stp[2] = xv4.z; stp[3] = xv4.w;
        if (ci + 1 < CIN) xv4 = ((const float4*)(xplane + (size_t)(ci + 1) * 1024))[t];
        float w9[9];
        {
            float sv = srow[ci];
            const float* wp = wrow + (size_t)ci * 9;
#pragma unroll
            for (int k = 0; k < 9; ++k) w9[k] = wp[k] * sv;
        }
        __syncthreads();               // xg ready
        if (t < 128) { if (active) do_ci<0>(xg + GUARD, w9, acc, xok, xbase); }
        else         { if (active) do_ci<1>(xg + GUARD, w9, acc, xok, xbase); }
    }

    // dump y registers to padded LDS plane (offset +1 in both dims)
    if (active) {
#pragma unroll
        for (int r = 0; r < 4; ++r) {
            int oy = 4 * rg + r;
            if (oy < 65) {
#pragma unroll
                for (int c = 0; c < 5; ++c)
                    ys[(oy + 1) * YSW + (c0 + c + 1)] = acc[r][c];
            }
        }
    }
    __syncthreads();

    // blur 4x4 (separable 1,3,3,1 /4 each axis), scale by d, add bias
    const float dv = dmod[b * COUT + co];
    const float bv = bias[co];
    const int px = t & 63, py0 = t >> 6;
    float* orow = out + (size_t)(b * COUT + co) * 4096;
    const float kv[4] = {0.25f, 0.75f, 0.75f, 0.25f};
#pragma unroll 4
    for (int j = 0; j < 16; ++j) {
        int py = py0 + 4 * j;
        float sum = 0.f;
#pragma unroll
        for (int u = 0; u < 4; ++u) {
            const float* yr = &ys[(py + u) * YSW + px];
            float rs = yr[0] * kv[0] + yr[1] * kv[1] + yr[2] * kv[2] + yr[3] * kv[3];
            sum = fmaf(rs, kv[u], sum);
        }
        orow[py * 64 + px] = dv * sum + bv;
    }
}

extern "C" void kernel_launch(void* const* d_in, const int* in_sizes, int n_in,
                              void* d_out, int out_size, void* d_ws, size_t ws_size,
                              hipStream_t stream) {
    const float* x      = (const float*)d_in[0];
    const float* w      = (const float*)d_in[1];
    const float* weight = (const float*)d_in[2];
    const float* bias   = (const float*)d_in[3];
    const float* aw     = (const float*)d_in[4];
    const float* ab     = (const float*)d_in[5];
    float* out = (float*)d_out;

    float* s    = (float*)d_ws;          // 16*512
    float* dmod = s + NB * CIN;          // 16*512
    float* wsq  = dmod + NB * COUT;      // 512*512

    k_style<<<NB, 512, 0, stream>>>(w, aw, ab, s);
    k_wsq<<<COUT, 512, 0, stream>>>(weight, wsq);
    k_demod<<<NB, 512, 0, stream>>>(s, wsq, dmod);
    k_main<<<NB * COUT, 256, 0, stream>>>(x, weight, s, dmod, bias, out);
}

// Round 2
// 451.681 us; speedup vs baseline: 5.4415x; 5.4415x over previous
//
#include <hip/hip_runtime.h>

#define CIN  512
#define COUT 512
#define LAT  512
#define NB   16

typedef __attribute__((ext_vector_type(8))) short bf16x8;
typedef __attribute__((ext_vector_type(4))) float f32x4;

__device__ __forceinline__ unsigned short f2bf(float f) {
    unsigned int u = __builtin_bit_cast(unsigned int, f);
    u += 0x7FFFu + ((u >> 16) & 1u);
    return (unsigned short)(u >> 16);
}

// ---------- s[b][ci] = w[b,:] . affine_w[ci,:] + ab[ci] + 1 ----------
__global__ void k_style(const float* __restrict__ w, const float* __restrict__ aw,
                        const float* __restrict__ ab, float* __restrict__ s) {
    int b = blockIdx.x, ci = threadIdx.x;
    __shared__ float wl[LAT];
    wl[ci] = w[b * LAT + ci];
    __syncthreads();
    const float4* awr = (const float4*)(aw + (size_t)ci * LAT);
    float acc = 0.f;
#pragma unroll 4
    for (int l = 0; l < LAT / 4; ++l) {
        float4 a4 = awr[l];
        const float* wp = &wl[l * 4];
        acc += a4.x * wp[0] + a4.y * wp[1] + a4.z * wp[2] + a4.w * wp[3];
    }
    s[b * CIN + ci] = acc + ab[ci] + 1.0f;
}

// ---------- wsq[co][ci] = sum_k weight[co,ci,k]^2 ----------
__global__ void k_wsq(const float* __restrict__ weight, float* __restrict__ wsq) {
    int co = blockIdx.x, ci = threadIdx.x;
    const float* p = weight + ((size_t)co * CIN + ci) * 9;
    float a = 0.f;
#pragma unroll
    for (int k = 0; k < 9; ++k) a += p[k] * p[k];
    wsq[co * CIN + ci] = a;
}

// ---------- d[b][co] = rsqrt(sum_ci s^2 * wsq + 1e-8) ----------
__global__ void k_demod(const float* __restrict__ s, const float* __restrict__ wsq,
                        float* __restrict__ d) {
    int b = blockIdx.x, co = threadIdx.x;
    __shared__ float s2[CIN];
    float sv = s[b * CIN + co];
    s2[co] = sv * sv;
    __syncthreads();
    const float4* wr = (const float4*)(wsq + (size_t)co * CIN);
    float acc = 0.f;
#pragma unroll 4
    for (int i = 0; i < CIN / 4; ++i) {
        float4 v = wr[i];
        const float* sp = &s2[i * 4];
        acc += v.x * sp[0] + v.y * sp[1] + v.z * sp[2] + v.w * sp[3];
    }
    d[b * COUT + co] = rsqrtf(acc + 1e-8f);
}

// ---------- A9[m=co*9+kk][ci] = bf16(weight[co][ci][kk]) ----------
__global__ void k_prepw(const float* __restrict__ weight, unsigned short* __restrict__ A9) {
    int co = blockIdx.x, t = threadIdx.x;
    __shared__ float wl[CIN * 9];
    const float* wp = weight + (size_t)co * CIN * 9;
    for (int i = t; i < CIN * 9; i += 256) wl[i] = wp[i];
    __syncthreads();
    unsigned short* ap = A9 + (size_t)co * 9 * CIN;
    for (int i = t; i < CIN * 9; i += 256) {
        int kk = i >> 9, ci = i & 511;
        ap[i] = f2bf(wl[ci * 9 + kk]);
    }
}

// ---------- XT[b][p][ci] = bf16(s[b][ci] * x[b][ci][p])  (64x64 LDS transpose) ----------
__global__ void k_prepx(const float* __restrict__ x, const float* __restrict__ s,
                        unsigned short* __restrict__ XT) {
    int blk = blockIdx.x;                 // 16b * 16pt * 8ct = 2048
    int b = blk >> 7, pt = (blk >> 3) & 15, ct = blk & 7;
    int p0 = pt * 64, ci0 = ct * 64;
    __shared__ float xt[64][65];
    __shared__ float ss[64];
    int t = threadIdx.x;
    if (t < 64) ss[t] = s[b * CIN + ci0 + t];
    const float* xb = x + ((size_t)(b * CIN + ci0)) * 1024 + p0;
#pragma unroll
    for (int rr = 0; rr < 4; ++rr) {
        int i = rr * 16 + (t >> 4), j = (t & 15) * 4;
        float4 v = *(const float4*)(xb + (size_t)i * 1024 + j);
        xt[i][j] = v.x; xt[i][j + 1] = v.y; xt[i][j + 2] = v.z; xt[i][j + 3] = v.w;
    }
    __syncthreads();
    unsigned short* xo = XT + ((size_t)(b * 1024 + p0)) * CIN + ci0;
#pragma unroll
    for (int rr = 0; rr < 4; ++rr) {
        int jj = rr * 16 + (t >> 4);
        int c4 = (t & 15) * 4;
        ushort4 o;
        o.x = f2bf(xt[c4][jj] * ss[c4]);
        o.y = f2bf(xt[c4 + 1][jj] * ss[c4 + 1]);
        o.z = f2bf(xt[c4 + 2][jj] * ss[c4 + 2]);
        o.w = f2bf(xt[c4 + 3][jj] * ss[c4 + 3]);
        *(ushort4*)(xo + (size_t)jj * CIN + c4) = o;
    }
}

// ---------- bf16 GEMM: C[4608][Ns] fp16 = A9[4608][512] x XT[Ns][512]^T ----------
__device__ __forceinline__ void gload16(const void* g, void* l) {
    __builtin_amdgcn_global_load_lds(
        (const __attribute__((address_space(1))) void*)g,
        (__attribute__((address_space(3))) void*)l, 16, 0, 0);
}

__device__ __forceinline__ unsigned int swz_goff(unsigned int o) {
    unsigned int row = o >> 6, kb = o & 63u;
    unsigned int kbx = kb ^ (((row >> 1) & 3u) << 4);
    return row * 1024u + kbx;
}

__launch_bounds__(256, 3)
__global__ void k_gemm(const unsigned short* __restrict__ A9,
                       const unsigned short* __restrict__ XT,
                       _Float16* __restrict__ C, int Ns) {
    __shared__ unsigned short smem[8192];      // A: bytes [0,8192), B: [8192,16384)
    const int t = threadIdx.x;
    const int bm = blockIdx.x, bn = blockIdx.y;

    // ---- staging addresses (4 x global_load_lds 16B per thread per K-step) ----
    const unsigned int o0 = (unsigned)t * 16u;          // r=0
    const unsigned int o1 = o0 + 4096u;                 // r=1
    char* lA0 = (char*)smem + ((t >> 6) * 1024);        // wave-uniform LDS bases
    char* lA1 = lA0 + 4096;
    char* lB0 = lA0 + 8192;
    char* lB1 = lA1 + 8192;
    const char* gA = (const char*)A9 + (size_t)bm * 128 * 1024;
    const char* gB = (const char*)XT + (size_t)bn * 128 * 1024;
    const char* pA0 = gA + swz_goff(o0);
    const char* pA1 = gA + swz_goff(o1);
    const char* pB0 = gB + swz_goff(o0);
    const char* pB1 = gB + swz_goff(o1);

    // ---- fragment read offsets (fixed, swizzled, conflict-free 2-way) ----
    const int lane = t & 63, w = t >> 6, wr = w >> 1, wc = w & 1;
    const int lrow = lane & 15;
    const unsigned int kbx = (unsigned)(((lane >> 4) << 4) ^ (((lrow >> 1) & 3) << 4));
    unsigned int offA[4], offB[4];
#pragma unroll
    for (int f = 0; f < 4; ++f) {
        offA[f] = (unsigned)((wr * 64 + f * 16 + lrow) * 64) + kbx;
        offB[f] = 8192u + (unsigned)((wc * 64 + f * 16 + lrow) * 64) + kbx;
    }

    f32x4 acc[4][4];
#pragma unroll
    for (int i = 0; i < 4; ++i)
#pragma unroll
        for (int j = 0; j < 4; ++j) acc[i][j] = (f32x4){0.f, 0.f, 0.f, 0.f};

    for (int it = 0; it < 16; ++it) {           // K = 512, BK = 32
        __syncthreads();                        // LDS free
        gload16(pA0, lA0); gload16(pA1, lA1);
        gload16(pB0, lB0); gload16(pB1, lB1);
        pA0 += 64; pA1 += 64; pB0 += 64; pB1 += 64;
        __syncthreads();                        // data ready (compiler drains vmcnt)
        bf16x8 a[4], b[4];
#pragma unroll
        for (int f = 0; f < 4; ++f) a[f] = *(const bf16x8*)((const char*)smem + offA[f]);
#pragma unroll
        for (int f = 0; f < 4; ++f) b[f] = *(const bf16x8*)((const char*)smem + offB[f]);
#pragma unroll
        for (int mf = 0; mf < 4; ++mf)
#pragma unroll
            for (int nf = 0; nf < 4; ++nf)
                acc[mf][nf] = __builtin_amdgcn_mfma_f32_16x16x32_bf16(
                    a[mf], b[nf], acc[mf][nf], 0, 0, 0);
    }

    const int mg0 = bm * 128 + wr * 64 + (lane >> 4) * 4;
    const int ng0 = bn * 128 + wc * 64 + (lane & 15);
#pragma unroll
    for (int mf = 0; mf < 4; ++mf)
#pragma unroll
        for (int j = 0; j < 4; ++j) {
            size_t row = (size_t)(mg0 + mf * 16 + j) * (size_t)Ns;
#pragma unroll
            for (int nf = 0; nf < 4; ++nf)
                C[row + ng0 + nf * 16] = (_Float16)acc[mf][nf][j];
        }
}

// ---------- scatter 9 taps -> y(65x65) in LDS, blur, demod, bias ----------
__global__ void k_scat(const _Float16* __restrict__ C, const float* __restrict__ dmod,
                       const float* __restrict__ bias, float* __restrict__ out,
                       int b0, int Ns) {
    const int blk = blockIdx.x;
    const int bl = blk >> 9, co = blk & 511, b = b0 + bl;
    const int t = threadIdx.x;
    __shared__ _Float16 ct[9][1024];
    __shared__ float ys[67 * 68];

    const _Float16* Cb = C + (size_t)(co * 9) * (size_t)Ns + bl * 1024;
#pragma unroll
    for (int k = 0; k < 9; ++k)
        ((ushort4*)ct[k])[t] = ((const ushort4*)(Cb + (size_t)k * Ns))[t];
    for (int i = t; i < 67 * 68; i += 256) ys[i] = 0.f;
    __syncthreads();

    for (int id = t; id < 65 * 65; id += 256) {
        int oy = id / 65, ox = id - oy * 65;
        int kys[2], iys[2], nk = 0;
        if (oy & 1) { kys[0] = 1; iys[0] = oy >> 1; nk = 1; }
        else {
            int h = oy >> 1;
            if (h < 32) { kys[0] = 0; iys[0] = h; nk = 1; }
            if (h >= 1) { kys[nk] = 2; iys[nk] = h - 1; nk++; }
        }
        int kxs[2], ixs[2], nx = 0;
        if (ox & 1) { kxs[0] = 1; ixs[0] = ox >> 1; nx = 1; }
        else {
            int h = ox >> 1;
            if (h < 32) { kxs[0] = 0; ixs[0] = h; nx = 1; }
            if (h >= 1) { kxs[nx] = 2; ixs[nx] = h - 1; nx++; }
        }
        float v = 0.f;
        for (int ia = 0; ia < nk; ++ia)
            for (int ic = 0; ic < nx; ++ic)
                v += (float)ct[kys[ia] * 3 + kxs[ic]][iys[ia] * 32 + ixs[ic]];
        ys[(oy + 1) * 68 + ox + 1] = v;
    }
    __syncthreads();

    const float dv = dmod[b * COUT + co];
    const float bv = bias[co];
    const int px = t & 63, py0 = t >> 6;
    float* orow = out + ((size_t)b * COUT + co) * 4096;
    const float kv[4] = {0.25f, 0.75f, 0.75f, 0.25f};
#pragma unroll 4
    for (int j = 0; j < 16; ++j) {
        int py = py0 + 4 * j;
        float sum = 0.f;
#pragma unroll
        for (int u = 0; u < 4; ++u) {
            const float* yr = &ys[(py + u) * 68 + px];
            float rs = yr[0] * kv[0] + yr[1] * kv[1] + yr[2] * kv[2] + yr[3] * kv[3];
            sum = fmaf(rs, kv[u], sum);
        }
        orow[py * 64 + px] = dv * sum + bv;
    }
}

extern "C" void kernel_launch(void* const* d_in, const int* in_sizes, int n_in,
                              void* d_out, int out_size, void* d_ws, size_t ws_size,
                              hipStream_t stream) {
    const float* x      = (const float*)d_in[0];
    const float* w      = (const float*)d_in[1];
    const float* weight = (const float*)d_in[2];
    const float* bias   = (const float*)d_in[3];
    const float* aw     = (const float*)d_in[4];
    const float* ab     = (const float*)d_in[5];
    float* out = (float*)d_out;

    char* wsb = (char*)d_ws;
    float* s            = (float*)wsb;                         // 32 KB
    float* dmod         = (float*)(wsb + 32768);               // 32 KB
    float* wsq          = (float*)(wsb + 65536);               // 1 MB
    unsigned short* A9  = (unsigned short*)(wsb + 1114112);    // 4.5 MB
    unsigned short* XT  = (unsigned short*)(wsb + 5832704);    // 16 MB
    _Float16* C         = (_Float16*)(wsb + 22609920);
    const size_t cbase  = 22609920;

    size_t avail = ws_size > cbase ? ws_size - cbase : 0;
    int nbc = 16;                                   // batches per chunk
    while (nbc > 1 && (size_t)4608 * 1024 * (size_t)nbc * 2 > avail) nbc >>= 1;

    k_style<<<NB, 512, 0, stream>>>(w, aw, ab, s);
    k_wsq<<<COUT, 512, 0, stream>>>(weight, wsq);
    k_demod<<<NB, 512, 0, stream>>>(s, wsq, dmod);
    k_prepw<<<COUT, 256, 0, stream>>>(weight, A9);
    k_prepx<<<2048, 256, 0, stream>>>(x, s, XT);

    const int Ns = nbc * 1024;
    for (int bb = 0; bb < NB; bb += nbc) {
        k_gemm<<<dim3(36, nbc * 8), 256, 0, stream>>>(A9, XT + (size_t)bb * 1024 * CIN, C, Ns);
        k_scat<<<nbc * 512, 256, 0, stream>>>(C, dmod, bias, out, bb, Ns);
    }
}